// Round 4
// baseline (243.636 us; speedup 1.0000x reference)
//
#include <hip/hip_runtime.h>

// Problem constants (fixed by setup_inputs): B=2, C=24, D=H=W=96.
static constexpr int   kS = 96 * 96 * 96;   // 884736 spatial positions per batch
static constexpr int   kC = 24;
static constexpr int   kB = 2;
static constexpr int   kN = kB * kS;        // 1769472 total positions
static constexpr float kSmooth = 1e-5f;
static constexpr int   kThreads = 256;
static constexpr int   kBlocks  = (kN / 4) / kThreads;   // 1728

// DENSE streaming version. R1-R3 showed guarded sparse loads run at ~half
// effective BW (256B DRAM granularity means P(chunk needed)=0.93 -> bytes
// saved are illusory, and ~10/64-active-lane loads waste issue BW).
// Here: every thread reads all 24 planes unconditionally -> perfectly
// coalesced dwordx4 streams, 177 MB fetched exactly once, BW-bound.
__global__ __launch_bounds__(kThreads) void mce_kernel(
    const float* __restrict__ logit0,
    const int*   __restrict__ target,
    const int*   __restrict__ cfb,      // class_for_batch, 12 ints
    float*       __restrict__ ws)       // kBlocks block partials
{
    // Present-class bitmask (wave-uniform scalar). Class 0 always present.
    unsigned present = 1u;
#pragma unroll
    for (int i = 0; i < 12; ++i) present |= (1u << cfb[i]);

    const int g    = blockIdx.x * kThreads + threadIdx.x;
    const int base = g * 4;             // 4 consecutive positions per thread

    // one coalesced 16B load of 4 targets
    const int4 t4 = reinterpret_cast<const int4*>(target)[g];
    const int t[4] = { t4.x, t4.y, t4.z, t4.w };

    // kS % 4 == 0, so a 4-group never crosses the batch boundary
    const int b  = (base >= kS) ? 1 : 0;
    const int s0 = base - b * kS;
    const float4* __restrict__ plane4 =
        reinterpret_cast<const float4*>(logit0 + (size_t)b * kC * kS + s0);

    float4 asum = make_float4(0.f, 0.f, 0.f, 0.f);  // absent-class sum
    float4 vsel = make_float4(0.f, 0.f, 0.f, 0.f);  // gathered logit0[b,t,s]

    // Groups of 8 planes: 8 independent dwordx4 loads in flight, then combine.
#pragma unroll
    for (int c0 = 0; c0 < kC; c0 += 8) {
        float4 x[8];
#pragma unroll
        for (int u = 0; u < 8; ++u)
            x[u] = plane4[(size_t)(c0 + u) * (kS / 4)];
#pragma unroll
        for (int u = 0; u < 8; ++u) {
            const int  c      = c0 + u;
            const bool absent = !((present >> c) & 1u);   // wave-uniform
            if (absent) {
                asum.x += x[u].x; asum.y += x[u].y;
                asum.z += x[u].z; asum.w += x[u].w;
            } else {
                vsel.x = (t[0] == c) ? x[u].x : vsel.x;
                vsel.y = (t[1] == c) ? x[u].y : vsel.y;
                vsel.z = (t[2] == c) ? x[u].z : vsel.z;
                vsel.w = (t[3] == c) ? x[u].w : vsel.w;
            }
        }
    }

    float acc = 0.0f;
    {
        const float vs[4] = { vsel.x, vsel.y, vsel.z, vsel.w };
        const float as[4] = { asum.x, asum.y, asum.z, asum.w };
#pragma unroll
        for (int j = 0; j < 4; ++j) {
            const int tj = t[j];
            float val = vs[j] + ((tj == 0) ? as[j] : 0.0f);
            val = fminf(fmaxf(val, kSmooth), 1.0f);
            const float ce = __logf(val) + kSmooth;
            acc += (((present >> tj) & 1u) ? ce : 0.0f);  // alpha in {0,1}
        }
    }

    // wave-64 butterfly reduce
#pragma unroll
    for (int off = 32; off > 0; off >>= 1)
        acc += __shfl_down(acc, off, 64);

    __shared__ float wave_sums[4];
    const int lane = threadIdx.x & 63;
    const int wid  = threadIdx.x >> 6;
    if (lane == 0) wave_sums[wid] = acc;
    __syncthreads();

    if (threadIdx.x == 0) {
        ws[blockIdx.x] = wave_sums[0] + wave_sums[1] + wave_sums[2] + wave_sums[3];
    }
}

// Single-block final reduction of the kBlocks partials. Writes d_out
// (poisoned to 0xAA before every timed launch) unconditionally.
__global__ __launch_bounds__(kThreads) void reduce_kernel(
    const float* __restrict__ ws, float* __restrict__ out)
{
    float acc = 0.0f;
    for (int i = threadIdx.x; i < kBlocks; i += kThreads) acc += ws[i];

#pragma unroll
    for (int off = 32; off > 0; off >>= 1)
        acc += __shfl_down(acc, off, 64);

    __shared__ float wave_sums[4];
    const int lane = threadIdx.x & 63;
    const int wid  = threadIdx.x >> 6;
    if (lane == 0) wave_sums[wid] = acc;
    __syncthreads();

    if (threadIdx.x == 0) {
        float s = wave_sums[0] + wave_sums[1] + wave_sums[2] + wave_sums[3];
        // loss = mean(-alpha * ce) = -(sum of ce) / N
        out[0] = s * (-1.0f / (float)kN);
    }
}

extern "C" void kernel_launch(void* const* d_in, const int* in_sizes, int n_in,
                              void* d_out, int out_size, void* d_ws, size_t ws_size,
                              hipStream_t stream)
{
    const float* logit0 = (const float*)d_in[0];
    const int*   target = (const int*)d_in[1];
    const int*   cfb    = (const int*)d_in[2];
    float*       out    = (float*)d_out;
    float*       ws     = (float*)d_ws;      // kBlocks floats << ws_size

    mce_kernel<<<kBlocks, kThreads, 0, stream>>>(logit0, target, cfb, ws);
    reduce_kernel<<<1, kThreads, 0, stream>>>(ws, out);
}

// Round 5
// 240.899 us; speedup vs baseline: 1.0114x; 1.0114x over previous
//
#include <hip/hip_runtime.h>

// Problem constants (fixed by setup_inputs): B=2, C=24, D=H=W=96.
static constexpr int   kS = 96 * 96 * 96;   // 884736 spatial positions per batch
static constexpr int   kC = 24;
static constexpr int   kB = 2;
static constexpr int   kN = kB * kS;        // 1769472 total positions
static constexpr float kSmooth = 1e-5f;
static constexpr int   kThreads = 256;
static constexpr int   kBlocks  = (kN / 4) / kThreads;   // 1728

// Dense streaming, ALL 24 plane loads issued upfront (max per-wave MLP;
// compiler drains vmcnt incrementally as the combine consumes x[0..23]).
// R4's groups-of-8 forced a full-latency stall at each group boundary.
__global__ __launch_bounds__(kThreads) void mce_kernel(
    const float* __restrict__ logit0,
    const int*   __restrict__ target,
    const int*   __restrict__ cfb,      // class_for_batch, 12 ints
    float*       __restrict__ ws)       // kBlocks block partials
{
    // Present-class bitmask (wave-uniform scalar). Class 0 always present.
    unsigned present = 1u;
#pragma unroll
    for (int i = 0; i < 12; ++i) present |= (1u << cfb[i]);

    const int g    = blockIdx.x * kThreads + threadIdx.x;
    const int base = g * 4;             // 4 consecutive positions per thread

    // one coalesced 16B load of 4 targets
    const int4 t4 = reinterpret_cast<const int4*>(target)[g];
    const int t[4] = { t4.x, t4.y, t4.z, t4.w };

    // kS % 4 == 0, so a 4-group never crosses the batch boundary
    const int b  = (base >= kS) ? 1 : 0;
    const int s0 = base - b * kS;
    const float4* __restrict__ plane4 =
        reinterpret_cast<const float4*>(logit0 + (size_t)b * kC * kS + s0);

    // Phase 1: issue ALL 24 independent dwordx4 loads (96 data VGPRs).
    float4 x[kC];
#pragma unroll
    for (int c = 0; c < kC; ++c)
        x[c] = plane4[(size_t)c * (kS / 4)];

    // Phase 2: combine. Consumes x[c] in order -> incremental vmcnt drain.
    float4 asum = make_float4(0.f, 0.f, 0.f, 0.f);  // absent-class sum
    float4 vsel = make_float4(0.f, 0.f, 0.f, 0.f);  // gathered logit0[b,t,s]
#pragma unroll
    for (int c = 0; c < kC; ++c) {
        // wave-uniform scalar mask: 1.0 for absent classes, else 0.0
        const float af = ((present >> c) & 1u) ? 0.0f : 1.0f;
        asum.x = fmaf(af, x[c].x, asum.x);
        asum.y = fmaf(af, x[c].y, asum.y);
        asum.z = fmaf(af, x[c].z, asum.z);
        asum.w = fmaf(af, x[c].w, asum.w);
        vsel.x = (t[0] == c) ? x[c].x : vsel.x;
        vsel.y = (t[1] == c) ? x[c].y : vsel.y;
        vsel.z = (t[2] == c) ? x[c].z : vsel.z;
        vsel.w = (t[3] == c) ? x[c].w : vsel.w;
    }

    float acc = 0.0f;
    {
        const float vs[4] = { vsel.x, vsel.y, vsel.z, vsel.w };
        const float as[4] = { asum.x, asum.y, asum.z, asum.w };
#pragma unroll
        for (int j = 0; j < 4; ++j) {
            const int tj = t[j];
            float val = vs[j] + ((tj == 0) ? as[j] : 0.0f);
            val = fminf(fmaxf(val, kSmooth), 1.0f);
            const float ce = __logf(val) + kSmooth;
            acc += (((present >> tj) & 1u) ? ce : 0.0f);  // alpha in {0,1}
        }
    }

    // wave-64 butterfly reduce
#pragma unroll
    for (int off = 32; off > 0; off >>= 1)
        acc += __shfl_down(acc, off, 64);

    __shared__ float wave_sums[4];
    const int lane = threadIdx.x & 63;
    const int wid  = threadIdx.x >> 6;
    if (lane == 0) wave_sums[wid] = acc;
    __syncthreads();

    if (threadIdx.x == 0) {
        ws[blockIdx.x] = wave_sums[0] + wave_sums[1] + wave_sums[2] + wave_sums[3];
    }
}

// Single-block final reduction of the kBlocks partials. Writes d_out
// (poisoned to 0xAA before every timed launch) unconditionally.
__global__ __launch_bounds__(kThreads) void reduce_kernel(
    const float* __restrict__ ws, float* __restrict__ out)
{
    float acc = 0.0f;
    for (int i = threadIdx.x; i < kBlocks; i += kThreads) acc += ws[i];

#pragma unroll
    for (int off = 32; off > 0; off >>= 1)
        acc += __shfl_down(acc, off, 64);

    __shared__ float wave_sums[4];
    const int lane = threadIdx.x & 63;
    const int wid  = threadIdx.x >> 6;
    if (lane == 0) wave_sums[wid] = acc;
    __syncthreads();

    if (threadIdx.x == 0) {
        float s = wave_sums[0] + wave_sums[1] + wave_sums[2] + wave_sums[3];
        // loss = mean(-alpha * ce) = -(sum of ce) / N
        out[0] = s * (-1.0f / (float)kN);
    }
}

extern "C" void kernel_launch(void* const* d_in, const int* in_sizes, int n_in,
                              void* d_out, int out_size, void* d_ws, size_t ws_size,
                              hipStream_t stream)
{
    const float* logit0 = (const float*)d_in[0];
    const int*   target = (const int*)d_in[1];
    const int*   cfb    = (const int*)d_in[2];
    float*       out    = (float*)d_out;
    float*       ws     = (float*)d_ws;      // kBlocks floats << ws_size

    mce_kernel<<<kBlocks, kThreads, 0, stream>>>(logit0, target, cfb, ws);
    reduce_kernel<<<1, kThreads, 0, stream>>>(ws, out);
}

// Round 6
// 238.943 us; speedup vs baseline: 1.0196x; 1.0082x over previous
//
#include <hip/hip_runtime.h>

// Problem constants (fixed by setup_inputs): B=2, C=24, D=H=W=96.
static constexpr int   kS = 96 * 96 * 96;   // 884736 spatial positions per batch
static constexpr int   kC = 24;
static constexpr int   kB = 2;
static constexpr int   kN = kB * kS;        // 1769472 total positions
static constexpr float kSmooth = 1e-5f;
static constexpr int   kThreads = 256;
static constexpr int   kQuads   = 4;                     // 4 float4 quads = 16 pos/thread
static constexpr int   kPosPerBlock = kThreads * kQuads * 4;   // 4096
static constexpr int   kBlocks  = kN / kPosPerBlock;     // 432

// Long-run dense streaming: plane loop is OUTER; each (block, plane) visit
// reads 16 KB contiguous (4 quads x 4 KB) before jumping to the next plane.
// R0-R5 variants all touched only 4 KB per (block,plane) -> ~18k concurrent
// 4KB streams at DRAM (short row runs). Double-buffered plane loads keep
// 4-8 dwordx4 in flight during the combine.
__global__ __launch_bounds__(kThreads) void mce_kernel(
    const float* __restrict__ logit0,
    const int*   __restrict__ target,
    const int*   __restrict__ cfb,      // class_for_batch, 12 ints
    float*       __restrict__ ws)       // kBlocks block partials
{
    // Present-class bitmask (wave-uniform scalar). Class 0 always present.
    unsigned present = 1u;
#pragma unroll
    for (int i = 0; i < 12; ++i) present |= (1u << cfb[i]);

    const int tid  = threadIdx.x;
    const int base = blockIdx.x * kPosPerBlock;   // global position base
    // kS % 4096 == 0 -> a block never straddles the batch boundary
    const int b  = (base >= kS) ? 1 : 0;
    const int s0 = base - b * kS;

    // targets for this thread's 16 positions (4 coalesced int4 loads)
    const int4* __restrict__ tgt4 =
        reinterpret_cast<const int4*>(target + (size_t)b * kS + s0);
    int t[kQuads][4];
#pragma unroll
    for (int q = 0; q < kQuads; ++q) {
        const int4 v = tgt4[q * kThreads + tid];
        t[q][0] = v.x; t[q][1] = v.y; t[q][2] = v.z; t[q][3] = v.w;
    }

    const float4* __restrict__ plane4 =
        reinterpret_cast<const float4*>(logit0 + (size_t)b * kC * kS + s0);

    float4 asum[kQuads], vsel[kQuads];
#pragma unroll
    for (int q = 0; q < kQuads; ++q) {
        asum[q] = make_float4(0.f, 0.f, 0.f, 0.f);
        vsel[q] = make_float4(0.f, 0.f, 0.f, 0.f);
    }

    // Double-buffered plane loop. quad q of plane c lives at
    // plane4[c*(kS/4) + q*kThreads + tid]  (4 KB per (wave,quad), 16 KB/block).
    float4 xa[kQuads], xb[kQuads];
#pragma unroll
    for (int q = 0; q < kQuads; ++q)
        xa[q] = plane4[q * kThreads + tid];

#pragma unroll
    for (int c = 0; c < kC; ++c) {
        if (c + 1 < kC) {
#pragma unroll
            for (int q = 0; q < kQuads; ++q)
                xb[q] = plane4[(size_t)(c + 1) * (kS / 4) + q * kThreads + tid];
        }
        const float af = ((present >> c) & 1u) ? 0.0f : 1.0f;  // wave-uniform
#pragma unroll
        for (int q = 0; q < kQuads; ++q) {
            asum[q].x = fmaf(af, xa[q].x, asum[q].x);
            asum[q].y = fmaf(af, xa[q].y, asum[q].y);
            asum[q].z = fmaf(af, xa[q].z, asum[q].z);
            asum[q].w = fmaf(af, xa[q].w, asum[q].w);
            vsel[q].x = (t[q][0] == c) ? xa[q].x : vsel[q].x;
            vsel[q].y = (t[q][1] == c) ? xa[q].y : vsel[q].y;
            vsel[q].z = (t[q][2] == c) ? xa[q].z : vsel[q].z;
            vsel[q].w = (t[q][3] == c) ? xa[q].w : vsel[q].w;
        }
#pragma unroll
        for (int q = 0; q < kQuads; ++q) xa[q] = xb[q];
    }

    // Per-position epilogue: clip, log, alpha-mask, accumulate.
    float acc = 0.0f;
#pragma unroll
    for (int q = 0; q < kQuads; ++q) {
        const float vs[4] = { vsel[q].x, vsel[q].y, vsel[q].z, vsel[q].w };
        const float as[4] = { asum[q].x, asum[q].y, asum[q].z, asum[q].w };
#pragma unroll
        for (int j = 0; j < 4; ++j) {
            const int tj = t[q][j];
            float val = vs[j] + ((tj == 0) ? as[j] : 0.0f);
            val = fminf(fmaxf(val, kSmooth), 1.0f);
            const float ce = __logf(val) + kSmooth;
            acc += (((present >> tj) & 1u) ? ce : 0.0f);  // alpha in {0,1}
        }
    }

    // wave-64 butterfly reduce
#pragma unroll
    for (int off = 32; off > 0; off >>= 1)
        acc += __shfl_down(acc, off, 64);

    __shared__ float wave_sums[4];
    const int lane = threadIdx.x & 63;
    const int wid  = threadIdx.x >> 6;
    if (lane == 0) wave_sums[wid] = acc;
    __syncthreads();

    if (threadIdx.x == 0) {
        ws[blockIdx.x] = wave_sums[0] + wave_sums[1] + wave_sums[2] + wave_sums[3];
    }
}

// Single-block final reduction of the kBlocks partials. Writes d_out
// (poisoned to 0xAA before every timed launch) unconditionally.
__global__ __launch_bounds__(kThreads) void reduce_kernel(
    const float* __restrict__ ws, float* __restrict__ out)
{
    float acc = 0.0f;
    for (int i = threadIdx.x; i < kBlocks; i += kThreads) acc += ws[i];

#pragma unroll
    for (int off = 32; off > 0; off >>= 1)
        acc += __shfl_down(acc, off, 64);

    __shared__ float wave_sums[4];
    const int lane = threadIdx.x & 63;
    const int wid  = threadIdx.x >> 6;
    if (lane == 0) wave_sums[wid] = acc;
    __syncthreads();

    if (threadIdx.x == 0) {
        float s = wave_sums[0] + wave_sums[1] + wave_sums[2] + wave_sums[3];
        // loss = mean(-alpha * ce) = -(sum of ce) / N
        out[0] = s * (-1.0f / (float)kN);
    }
}

extern "C" void kernel_launch(void* const* d_in, const int* in_sizes, int n_in,
                              void* d_out, int out_size, void* d_ws, size_t ws_size,
                              hipStream_t stream)
{
    const float* logit0 = (const float*)d_in[0];
    const int*   target = (const int*)d_in[1];
    const int*   cfb    = (const int*)d_in[2];
    float*       out    = (float*)d_out;
    float*       ws     = (float*)d_ws;      // kBlocks floats << ws_size

    mce_kernel<<<kBlocks, kThreads, 0, stream>>>(logit0, target, cfb, ws);
    reduce_kernel<<<1, kThreads, 0, stream>>>(ws, out);
}